// Round 9
// baseline (210.409 us; speedup 1.0000x reference)
//
#include <hip/hip_runtime.h>

#define EMBED 1024
#define HEADS 16
#define HDIM 64
#define SQ 1023        // word sequence length
#define SK 1024        // key rows per (b,h): 1023 word tokens + row 1023 = image k
#define MTOK 4092      // 4*1023 valid token rows
#define MPAD 4096      // padded to 128 multiple

typedef __attribute__((ext_vector_type(8))) short short8;
typedef __attribute__((ext_vector_type(4))) float floatx4;

static __device__ __forceinline__ unsigned short f2bf(float f) {
  union { float f; unsigned u; } v; v.f = f;
  unsigned u = v.u;
  u += 0x7fffu + ((u >> 16) & 1u);
  return (unsigned short)(u >> 16);
}
static __device__ __forceinline__ float bf2f(unsigned short s) {
  union { unsigned u; float f; } v; v.u = ((unsigned)s) << 16;
  return v.f;
}

// async global->LDS, 16B per lane. LDS dest = wave-uniform base + lane*16.
static __device__ __forceinline__ void gld16(const unsigned short* g, unsigned short* l) {
  typedef const __attribute__((address_space(1))) unsigned int guint;
  typedef __attribute__((address_space(3))) unsigned int luint;
  __builtin_amdgcn_global_load_lds((guint*)(const void*)g, (luint*)(void*)l, 16, 0, 0);
}

// DPP rotate within 16-lane rows (pure VALU — no LDS latency). Validated R7/R8.
template <int CTRL>
static __device__ __forceinline__ float rorf(float x) {
  union { float f; int i; } v; v.f = x;
  v.i = __builtin_amdgcn_update_dpp(v.i, v.i, CTRL, 0xF, 0xF, true);
  return v.f;
}

// ---------------- fused prep kernel ----------------
__global__ __launch_bounds__(256) void k_prep(
    const float* __restrict__ word, const float* __restrict__ attn_w,
    const float* __restrict__ proj_w, const float* __restrict__ img,
    const float* __restrict__ ukw, const float* __restrict__ ukb,
    const float* __restrict__ uvw, const float* __restrict__ uvb,
    unsigned short* __restrict__ A, unsigned short* __restrict__ WtA,
    unsigned short* __restrict__ WtP, unsigned short* __restrict__ Qb,
    unsigned short* __restrict__ Kb, unsigned short* __restrict__ Vt) {
  __shared__ float T[32][33];
  int bx = blockIdx.x, t = threadIdx.x;
  if (bx < 2048) {
    int idx = (bx * 256 + t) * 8;
    int row = idx >> 10;
    short8 v;
    if (row < MTOK) {
      const float4* p = (const float4*)(word + idx);
      float4 a = p[0], b = p[1];
      v[0] = (short)f2bf(a.x); v[1] = (short)f2bf(a.y);
      v[2] = (short)f2bf(a.z); v[3] = (short)f2bf(a.w);
      v[4] = (short)f2bf(b.x); v[5] = (short)f2bf(b.y);
      v[6] = (short)f2bf(b.z); v[7] = (short)f2bf(b.w);
    } else {
#pragma unroll
      for (int i = 0; i < 8; i++) v[i] = 0;
    }
    *(short8*)(A + idx) = v;
  } else if (bx < 6144) {
    const float* W; unsigned short* Wt; int N, n0, k0;
    if (bx < 5120) {
      int r = bx - 2048; W = attn_w; Wt = WtA; N = 3072;
      n0 = (r % 96) * 32; k0 = (r / 96) * 32;
    } else {
      int r = bx - 5120; W = proj_w; Wt = WtP; N = 1024;
      n0 = (r & 31) * 32; k0 = (r >> 5) * 32;
    }
    int tx = t & 31, ty = t >> 5;
#pragma unroll
    for (int i = 0; i < 4; i++) {
      int r = ty + i * 8;
      T[r][tx] = W[(k0 + r) * N + n0 + tx];
    }
    __syncthreads();
#pragma unroll
    for (int i = 0; i < 4; i++) {
      int r = ty + i * 8;
      Wt[(n0 + r) * 1024 + k0 + tx] = f2bf(T[tx][r]);
    }
  } else if (bx < 8192) {
    int wid = (bx - 6144) * 4 + (t >> 6);
    int lane = t & 63;
    int which = wid >> 12;            // 0: k, 1: v
    int bb = (wid >> 10) & 3;
    int n = wid & 1023;
    const float* W = which ? uvw : ukw;
    const float* bias = which ? uvb : ukb;
    const float* x = img + bb * 1024;
    const float* w = W + n * 1024;
    float s = 0.f;
#pragma unroll
    for (int i = 0; i < 16; i++) { int k = i * 64 + lane; s += x[k] * w[k]; }
#pragma unroll
    for (int off = 32; off; off >>= 1) s += __shfl_xor(s, off);
    if (lane == 0) {
      int h = n >> 6, d = n & 63;
      unsigned short val = f2bf(s + bias[n]);
      if (which == 0) Kb[((bb * HEADS + h) * SK + (SK - 1)) * HDIM + d] = val;
      else            Vt[((bb * HEADS + h) * HDIM + d) * SK + (SK - 1)] = val;
    }
  } else {
    int i = (bx - 8192) * 256 + t;    // 4096 = 64 bh * 64 d
    int bh = i >> 6, d = i & 63;
    Qb[(bh * SK + (SK - 1)) * HDIM + d] = 0;
  }
}

// ---------------- MFMA GEMM: C[m][n] = sum_k A[m][k]*Bt[n][k] (+bias) ----------------
template <int EPI, int TN>
__global__ __launch_bounds__(256, 2) void k_gemm(
    const unsigned short* __restrict__ A, const unsigned short* __restrict__ Bt,
    int Kdim, const float* __restrict__ bias,
    unsigned short* __restrict__ Qb, unsigned short* __restrict__ Kb,
    unsigned short* __restrict__ VtOut, float* __restrict__ out) {
  constexpr int NC = TN / 32;            // nc frags per wave (6 or 4)
  __shared__ __attribute__((aligned(16))) unsigned short Sm[8192 + TN * 64];
  unsigned short* As = Sm;               // [128][64], xor-swizzled
  unsigned short* Bs = Sm + 8192;        // [TN][64], xor-swizzled
  int t = threadIdx.x, lane = t & 63, w = t >> 6;
  int quad = lane >> 4, l16 = lane & 15;
  int m0 = blockIdx.y * 128, n0 = blockIdx.x * TN;
  int waveM = (w >> 1) * 64, waveN = (w & 1) * (TN / 2);
  int rs = t >> 3, cs = t & 7;

  floatx4 acc[4][NC];
#pragma unroll
  for (int i = 0; i < 4; i++)
#pragma unroll
    for (int j = 0; j < NC; j++)
#pragma unroll
      for (int e = 0; e < 4; e++) acc[i][j][e] = 0.f;

  const unsigned short* Ag = A + m0 * Kdim;
  const unsigned short* Bg = Bt + n0 * Kdim;

  for (int k0 = 0; k0 < Kdim; k0 += 64) {
    __syncthreads();
#pragma unroll
    for (int i = 0; i < 4; i++) {
      int r = i * 32 + rs;
      gld16(Ag + r * Kdim + k0 + ((cs ^ (r & 7)) * 8), As + i * 2048 + t * 8);
    }
#pragma unroll
    for (int i = 0; i < TN / 32; i++) {
      int r = i * 32 + rs;
      gld16(Bg + r * Kdim + k0 + ((cs ^ (r & 7)) * 8), Bs + i * 2048 + t * 8);
    }
    __syncthreads();
#pragma unroll
    for (int kk = 0; kk < 2; kk++) {
      short8 af[4], bf8[NC];
#pragma unroll
      for (int mr = 0; mr < 4; mr++) {
        int row = waveM + mr * 16 + l16;
        af[mr] = *(const short8*)(As + row * 64 + (((kk * 4 + quad) ^ (row & 7)) * 8));
      }
#pragma unroll
      for (int nc = 0; nc < NC; nc++) {
        int row = waveN + nc * 16 + l16;
        bf8[nc] = *(const short8*)(Bs + row * 64 + (((kk * 4 + quad) ^ (row & 7)) * 8));
      }
#pragma unroll
      for (int mr = 0; mr < 4; mr++)
#pragma unroll
        for (int nc = 0; nc < NC; nc++)
          acc[mr][nc] = __builtin_amdgcn_mfma_f32_16x16x32_bf16(af[mr], bf8[nc], acc[mr][nc], 0, 0, 0);
    }
  }

  float bv[NC];
#pragma unroll
  for (int nc = 0; nc < NC; nc++) bv[nc] = bias[n0 + waveN + nc * 16 + l16];

  if (EPI == 0) {
    unsigned short* Cs = Sm;
    const int CST = 208;
    int startV = 2048 - n0;
    if (startV < 0) startV = 0;
    if (startV > TN) startV = TN;
    int chunksQK = startV >> 3;
    for (int p = 0; p < 2; p++) {
      __syncthreads();
      if ((w >> 1) == p) {
#pragma unroll
        for (int mr = 0; mr < 4; mr++)
#pragma unroll
          for (int nc = 0; nc < NC; nc++)
#pragma unroll
            for (int r = 0; r < 4; r++) {
              int lrow = mr * 16 + quad * 4 + r;
              int lcol = waveN + nc * 16 + l16;
              Cs[lrow * CST + (((lcol >> 3) ^ (quad << 1)) * 8) + (lcol & 7)] =
                  f2bf(acc[mr][nc][r] + bv[nc]);
            }
      }
      __syncthreads();
      {
        int lr = t & 63, gm = m0 + p * 64 + lr;
        int rot = ((lr >> 2) & 3) << 1;
        bool okm = (gm < MTOK);
        int bb = (unsigned)gm / 1023u;
        int s = gm - bb * 1023;
        for (int c8 = (t >> 6); c8 < chunksQK; c8 += 4) {
          short8 v = *(const short8*)(Cs + lr * CST + ((c8 ^ rot) * 8));
          int gn = n0 + c8 * 8;
          unsigned short* dst = (gn >> 10) ? Kb : Qb;
          int e = gn & 1023;
          int h = e >> 6, d0 = e & 63;
          if (okm) *(short8*)(dst + ((bb * HEADS + h) * SK + s) * HDIM + d0) = v;
        }
      }
      {
        int tok = t & 63, gm = m0 + p * 64 + tok;
        int rot = ((tok >> 2) & 3) << 1;
        bool okm = (gm < MTOK);
        int bb = (unsigned)gm / 1023u;
        int s = gm - bb * 1023;
        for (int c = startV + (t >> 6); c < TN; c += 4) {
          unsigned short val = Cs[tok * CST + (((c >> 3) ^ rot) * 8) + (c & 7)];
          int e = (n0 + c) & 1023;
          int h = e >> 6, d0 = e & 63;
          if (okm) VtOut[((bb * HEADS + h) * HDIM + d0) * SK + s] = val;
        }
      }
    }
  } else {
#pragma unroll
    for (int nc = 0; nc < NC; nc++) {
      int gn = n0 + waveN + nc * 16 + l16;
#pragma unroll
      for (int mr = 0; mr < 4; mr++) {
#pragma unroll
        for (int r = 0; r < 4; r++) {
          int gm = m0 + waveM + mr * 16 + quad * 4 + r;
          if (gm < MTOK) out[gm * EMBED + gn] = acc[mr][nc][r] + bv[nc];
        }
      }
    }
  }
}

// ---------------- flash attention ----------------
// R8 structure + fixed-shift softmax (m = image score, alpha == 1; masked entries
// underflow to 0 via exp2(-14427); row-sum reduced ONCE at the end — valid because
// with fixed shift the sum is commutative across tiles) + Ps halved to 8KB (P packed
// and consumed in two 64-key halves; per-wave in-order DS ordering makes the reuse
// safe). LDS 40KB -> 4 blocks/CU.
__global__ __launch_bounds__(256, 4) void k_flash(
    const unsigned short* __restrict__ Qb, const unsigned short* __restrict__ Kb,
    const unsigned short* __restrict__ Vtg, const float* __restrict__ am,
    unsigned short* __restrict__ Ao) {
  __shared__ __attribute__((aligned(16))) unsigned short Ks[8192];   // [128][64] xor-swz
  __shared__ __attribute__((aligned(16))) unsigned short Vs[8192];   // [64 d][128 key] xor-swz
  __shared__ __attribute__((aligned(16))) unsigned short Ps[4096];   // 4 waves x [16][64] xor-swz

  int t = threadIdx.x, lane = t & 63, w = t >> 6;
  int quad = lane >> 4, l16 = lane & 15;
  int B = blockIdx.x;
  int bh = (B & 7) | (((B >> 3) & 7) << 3);
  int tq = 15 - (B >> 6);             // heavy blocks dispatch first
  int bb = bh >> 4, h = bh & 15;

  const float SCL = 0.18033688011f;     // 0.125 * log2(e)
  const float MASKV = -14426.950408f;   // -10000 * log2(e)
  const float L2E = 1.44269504089f;

  // Q fragments in registers (row 1023 is the zeroed pad)
  short8 qf[2];
  {
    int qrow = tq * 64 + w * 16 + l16;
#pragma unroll
    for (int kk = 0; kk < 2; kk++)
      qf[kk] = *(const short8*)(Qb + (bh * SK + qrow) * HDIM + (kk * 4 + quad) * 8);
  }

  // image init: m = (q . k_img)*SCL (fixed shift), implicit p_img = 1, O = v_img
  float m_i[4];
  floatx4 acc_o[4];
  {
    float s0 = 0.f;
#pragma unroll
    for (int kk = 0; kk < 2; kk++) {
      short8 ki = *(const short8*)(Kb + (bh * SK + (SK - 1)) * HDIM + (kk * 4 + quad) * 8);
#pragma unroll
      for (int j = 0; j < 8; j++)
        s0 += bf2f((unsigned short)qf[kk][j]) * bf2f((unsigned short)ki[j]);
    }
    s0 += __shfl_xor(s0, 16);
    s0 += __shfl_xor(s0, 32);
    s0 *= SCL;
#pragma unroll
    for (int r = 0; r < 4; r++) m_i[r] = __shfl(s0, quad * 4 + r);
#pragma unroll
    for (int n = 0; n < 4; n++) {
      float vf = bf2f(Vtg[(bh * HDIM + n * 16 + l16) * SK + (SK - 1)]);
#pragma unroll
      for (int e = 0; e < 4; e++) acc_o[n][e] = vf;
    }
  }

  float rsum_t[4] = {0.f, 0.f, 0.f, 0.f};   // per-lane partial, reduced once at end
  unsigned short* Pw = Ps + w * 1024;       // [16][64] per wave
  const float* amb = am + bb * SQ;
  int jmax = tq >> 1;

  for (int j = 0; j <= jmax; j++) {
    __syncthreads();   // prior readers done (drains pending GLDs too)
#pragma unroll
    for (int i = 0; i < 4; i++) {
      int r = i * 32 + (t >> 3), gc = (t & 7) ^ (r & 7);
      gld16(Kb + (bh * SK + j * 128 + r) * HDIM + gc * 8, Ks + i * 2048 + t * 8);
    }
#pragma unroll
    for (int i = 0; i < 4; i++) {
      int d = i * 16 + (t >> 4), gc = (t & 15) ^ (d & 7);
      gld16(Vtg + (bh * HDIM + d) * SK + j * 128 + gc * 8, Vs + i * 2048 + t * 8);
    }
    __syncthreads();

    bool diag = (j == jmax);
    int qmaxw = tq * 64 + w * 16 + 15;   // max q row this wave owns

    floatx4 sacc[8];
#pragma unroll
    for (int n = 0; n < 8; n++)
#pragma unroll
      for (int e = 0; e < 4; e++) sacc[n][e] = 0.f;
#pragma unroll
    for (int nc = 0; nc < 8; nc++) {
      if (j * 128 + nc * 16 <= qmaxw) {
        int krow = nc * 16 + l16;
#pragma unroll
        for (int kk = 0; kk < 2; kk++) {
          short8 b = *(const short8*)(Ks + krow * 64 + (((kk * 4 + quad) ^ (krow & 7)) * 8));
          sacc[nc] = __builtin_amdgcn_mfma_f32_16x16x32_bf16(qf[kk], b, sacc[nc], 0, 0, 0);
        }
      }
    }

    // p = exp2(sc - m_fixed); masked entries underflow to exactly 0.
    int qbase = tq * 64 + w * 16 + quad * 4;
#pragma unroll
    for (int nc = 0; nc < 8; nc++) {
      if (j * 128 + nc * 16 <= qmaxw) {     // dead nc: sacc stays 0 (never QK'd)
        int s = j * 128 + nc * 16 + l16;
        float amv = (s < SQ) ? amb[s] * L2E : 0.f;
#pragma unroll
        for (int r = 0; r < 4; r++) {
          float sc = sacc[nc][r] * SCL + amv;
          if (diag && s > qbase + r) sc = MASKV;
          float p = __builtin_amdgcn_exp2f(sc - m_i[r]);
          sacc[nc][r] = p;
          rsum_t[r] += p;
        }
      }
    }

    // P pack + PV in two 64-key halves (Pw reused; in-wave DS order = safe)
#pragma unroll
    for (int hh = 0; hh < 2; hh++) {
      if (j * 128 + hh * 64 <= qmaxw) {
#pragma unroll
        for (int nc2 = 0; nc2 < 4; nc2++) {
          int nc = hh * 4 + nc2;
#pragma unroll
          for (int r = 0; r < 4; r++) {
            int row = quad * 4 + r;
            union { float f; unsigned u; } cv; cv.f = sacc[nc][r];
            Pw[row * 64 + (((nc2 * 2 + (l16 >> 3)) ^ (row & 7)) * 8) + (l16 & 7)] =
                (unsigned short)(cv.u >> 16);
          }
        }
#pragma unroll
        for (int k2 = 0; k2 < 2; k2++) {
          int kk2 = hh * 2 + k2;
          short8 a = *(const short8*)(Pw + l16 * 64 + (((k2 * 4 + quad) ^ (l16 & 7)) * 8));
#pragma unroll
          for (int n = 0; n < 4; n++) {
            int vrow = n * 16 + l16;
            short8 b = *(const short8*)(Vs + vrow * 128 + (((kk2 * 4 + quad) ^ (vrow & 7)) * 8));
            acc_o[n] = __builtin_amdgcn_mfma_f32_16x16x32_bf16(a, b, acc_o[n], 0, 0, 0);
          }
        }
      }
    }
  }

  // single final row-reduce of the sum; l = 1 (image) + rsum
  float inv[4];
#pragma unroll
  for (int r = 0; r < 4; r++) {
    float o = rsum_t[r];
    o += rorf<0x121>(o);
    o += rorf<0x122>(o);
    o += rorf<0x124>(o);
    o += rorf<0x128>(o);
    inv[r] = 1.f / (1.f + o);
  }

  // normalize, repack via LDS (Os overlays Ps), vectorized store
  unsigned short* Os = Ps;   // [64][64], "+row" chunk rotation
  __syncthreads();
#pragma unroll
  for (int n = 0; n < 4; n++)
#pragma unroll
    for (int r = 0; r < 4; r++) {
      int row = w * 16 + quad * 4 + r, col = n * 16 + l16;
      Os[row * 64 + ((((col >> 3) + row) & 7) * 8) + (col & 7)] = f2bf(acc_o[n][r] * inv[r]);
    }
  __syncthreads();
#pragma unroll
  for (int i = 0; i < 2; i++) {
    int cid = i * 256 + t, r = cid >> 3, c8 = cid & 7;
    int q = tq * 64 + r;
    if (q < SQ) {
      short8 v = *(const short8*)(Os + r * 64 + (((c8 + r) & 7) * 8));
      *(short8*)(Ao + (bb * SQ + q) * EMBED + h * HDIM + c8 * 8) = v;
    }
  }
}

// ---------------- launch ----------------
extern "C" void kernel_launch(void* const* d_in, const int* in_sizes, int n_in,
                              void* d_out, int out_size, void* d_ws, size_t ws_size,
                              hipStream_t stream) {
  const float* word   = (const float*)d_in[0];
  const float* img    = (const float*)d_in[1];
  const float* amask  = (const float*)d_in[2];
  const float* attn_w = (const float*)d_in[3];
  const float* attn_b = (const float*)d_in[4];
  const float* proj_w = (const float*)d_in[5];
  const float* proj_b = (const float*)d_in[6];
  const float* ukw    = (const float*)d_in[7];
  const float* ukb    = (const float*)d_in[8];
  const float* uvw    = (const float*)d_in[9];
  const float* uvb    = (const float*)d_in[10];
  float* out = (float*)d_out;

  char* ws = (char*)d_ws;
  unsigned short* Aw     = (unsigned short*)(ws);                 // [0,8MB) A / later Ao
  unsigned short* WtAttn = (unsigned short*)(ws + 8388608);       // [8,14MB)
  unsigned short* WtProj = (unsigned short*)(ws + 14680064);      // [14,16MB)
  unsigned short* Qb     = (unsigned short*)(ws + 16777216);      // [16,24MB)
  unsigned short* Kb     = (unsigned short*)(ws + 25165824);      // [24,32MB) row 1023 = k_img
  unsigned short* Vtg    = (unsigned short*)(ws + 33554432);      // [32,40MB) V^T, col 1023 = v_img
  unsigned short* Ao     = Aw;  // reuse: A dead after QKV GEMM

  k_prep<<<8208, 256, 0, stream>>>(word, attn_w, proj_w, img, ukw, ukb, uvw, uvb,
                                   Aw, WtAttn, WtProj, Qb, Kb, Vtg);
  k_gemm<0, 192><<<dim3(16, 32), 256, 0, stream>>>(Aw, WtAttn, 1024, attn_b, Qb, Kb, Vtg, nullptr);
  k_flash<<<1024, 256, 0, stream>>>(Qb, Kb, Vtg, amask, Ao);
  k_gemm<1, 128><<<dim3(8, 32), 256, 0, stream>>>(Ao, WtProj, 1024, proj_b, nullptr, nullptr, nullptr, out);
}

// Round 10
// 192.185 us; speedup vs baseline: 1.0948x; 1.0948x over previous
//
#include <hip/hip_runtime.h>

#define EMBED 1024
#define HEADS 16
#define HDIM 64
#define SQ 1023        // word sequence length
#define SK 1024        // key rows per (b,h): 1023 word tokens + row 1023 = image k
#define MTOK 4092      // 4*1023 valid token rows
#define MPAD 4096      // padded to 128 multiple

typedef __attribute__((ext_vector_type(8))) short short8;
typedef __attribute__((ext_vector_type(4))) float floatx4;

static __device__ __forceinline__ unsigned short f2bf(float f) {
  union { float f; unsigned u; } v; v.f = f;
  unsigned u = v.u;
  u += 0x7fffu + ((u >> 16) & 1u);
  return (unsigned short)(u >> 16);
}
static __device__ __forceinline__ float bf2f(unsigned short s) {
  union { unsigned u; float f; } v; v.u = ((unsigned)s) << 16;
  return v.f;
}

// async global->LDS, 16B per lane. LDS dest = wave-uniform base + lane*16.
static __device__ __forceinline__ void gld16(const unsigned short* g, unsigned short* l) {
  typedef const __attribute__((address_space(1))) unsigned int guint;
  typedef __attribute__((address_space(3))) unsigned int luint;
  __builtin_amdgcn_global_load_lds((guint*)(const void*)g, (luint*)(void*)l, 16, 0, 0);
}

// DPP rotate within 16-lane rows (pure VALU — no LDS latency). Validated R7/R8.
template <int CTRL>
static __device__ __forceinline__ float rorf(float x) {
  union { float f; int i; } v; v.f = x;
  v.i = __builtin_amdgcn_update_dpp(v.i, v.i, CTRL, 0xF, 0xF, true);
  return v.f;
}

// ---------------- fused prep kernel ----------------
__global__ __launch_bounds__(256) void k_prep(
    const float* __restrict__ word, const float* __restrict__ attn_w,
    const float* __restrict__ proj_w, const float* __restrict__ img,
    const float* __restrict__ ukw, const float* __restrict__ ukb,
    const float* __restrict__ uvw, const float* __restrict__ uvb,
    unsigned short* __restrict__ A, unsigned short* __restrict__ WtA,
    unsigned short* __restrict__ WtP, unsigned short* __restrict__ Qb,
    unsigned short* __restrict__ Kb, unsigned short* __restrict__ Vt) {
  __shared__ float T[32][33];
  int bx = blockIdx.x, t = threadIdx.x;
  if (bx < 2048) {
    int idx = (bx * 256 + t) * 8;
    int row = idx >> 10;
    short8 v;
    if (row < MTOK) {
      const float4* p = (const float4*)(word + idx);
      float4 a = p[0], b = p[1];
      v[0] = (short)f2bf(a.x); v[1] = (short)f2bf(a.y);
      v[2] = (short)f2bf(a.z); v[3] = (short)f2bf(a.w);
      v[4] = (short)f2bf(b.x); v[5] = (short)f2bf(b.y);
      v[6] = (short)f2bf(b.z); v[7] = (short)f2bf(b.w);
    } else {
#pragma unroll
      for (int i = 0; i < 8; i++) v[i] = 0;
    }
    *(short8*)(A + idx) = v;
  } else if (bx < 6144) {
    const float* W; unsigned short* Wt; int N, n0, k0;
    if (bx < 5120) {
      int r = bx - 2048; W = attn_w; Wt = WtA; N = 3072;
      n0 = (r % 96) * 32; k0 = (r / 96) * 32;
    } else {
      int r = bx - 5120; W = proj_w; Wt = WtP; N = 1024;
      n0 = (r & 31) * 32; k0 = (r >> 5) * 32;
    }
    int tx = t & 31, ty = t >> 5;
#pragma unroll
    for (int i = 0; i < 4; i++) {
      int r = ty + i * 8;
      T[r][tx] = W[(k0 + r) * N + n0 + tx];
    }
    __syncthreads();
#pragma unroll
    for (int i = 0; i < 4; i++) {
      int r = ty + i * 8;
      Wt[(n0 + r) * 1024 + k0 + tx] = f2bf(T[tx][r]);
    }
  } else if (bx < 8192) {
    int wid = (bx - 6144) * 4 + (t >> 6);
    int lane = t & 63;
    int which = wid >> 12;            // 0: k, 1: v
    int bb = (wid >> 10) & 3;
    int n = wid & 1023;
    const float* W = which ? uvw : ukw;
    const float* bias = which ? uvb : ukb;
    const float* x = img + bb * 1024;
    const float* w = W + n * 1024;
    float s = 0.f;
#pragma unroll
    for (int i = 0; i < 16; i++) { int k = i * 64 + lane; s += x[k] * w[k]; }
#pragma unroll
    for (int off = 32; off; off >>= 1) s += __shfl_xor(s, off);
    if (lane == 0) {
      int h = n >> 6, d = n & 63;
      unsigned short val = f2bf(s + bias[n]);
      if (which == 0) Kb[((bb * HEADS + h) * SK + (SK - 1)) * HDIM + d] = val;
      else            Vt[((bb * HEADS + h) * HDIM + d) * SK + (SK - 1)] = val;
    }
  } else {
    int i = (bx - 8192) * 256 + t;    // 4096 = 64 bh * 64 d
    int bh = i >> 6, d = i & 63;
    Qb[(bh * SK + (SK - 1)) * HDIM + d] = 0;
  }
}

// ---------------- MFMA GEMM: C[m][n] = sum_k A[m][k]*Bt[n][k] (+bias) ----------------
// TM x TN tile, 4 waves (2x2), wave tile (TM/2) x (TN/2), BK=64, gld16 staging.
// EPI 0 (128x192): head-split scatter (512 blocks = 2/CU, single round).
// EPI 1 (64x128): f32 row-major store (512 blocks = 2/CU — was 256, latency-exposed).
template <int EPI, int TM, int TN>
__global__ __launch_bounds__(256, 2) void k_gemm(
    const unsigned short* __restrict__ A, const unsigned short* __restrict__ Bt,
    int Kdim, const float* __restrict__ bias,
    unsigned short* __restrict__ Qb, unsigned short* __restrict__ Kb,
    unsigned short* __restrict__ VtOut, float* __restrict__ out) {
  constexpr int MR = TM / 32;            // m frags per wave
  constexpr int NC = TN / 32;            // n frags per wave
  __shared__ __attribute__((aligned(16))) unsigned short Sm[(TM + TN) * 64];
  unsigned short* As = Sm;               // [TM][64], xor-swizzled
  unsigned short* Bs = Sm + TM * 64;     // [TN][64], xor-swizzled
  int t = threadIdx.x, lane = t & 63, w = t >> 6;
  int quad = lane >> 4, l16 = lane & 15;
  int m0 = blockIdx.y * TM, n0 = blockIdx.x * TN;
  int waveM = (w >> 1) * (TM / 2), waveN = (w & 1) * (TN / 2);
  int rs = t >> 3, cs = t & 7;

  floatx4 acc[MR][NC];
#pragma unroll
  for (int i = 0; i < MR; i++)
#pragma unroll
    for (int j = 0; j < NC; j++)
#pragma unroll
      for (int e = 0; e < 4; e++) acc[i][j][e] = 0.f;

  const unsigned short* Ag = A + m0 * Kdim;
  const unsigned short* Bg = Bt + n0 * Kdim;

  for (int k0 = 0; k0 < Kdim; k0 += 64) {
    __syncthreads();
#pragma unroll
    for (int i = 0; i < TM / 32; i++) {
      int r = i * 32 + rs;
      gld16(Ag + r * Kdim + k0 + ((cs ^ (r & 7)) * 8), As + i * 2048 + t * 8);
    }
#pragma unroll
    for (int i = 0; i < TN / 32; i++) {
      int r = i * 32 + rs;
      gld16(Bg + r * Kdim + k0 + ((cs ^ (r & 7)) * 8), Bs + i * 2048 + t * 8);
    }
    __syncthreads();
#pragma unroll
    for (int kk = 0; kk < 2; kk++) {
      short8 af[MR], bf8[NC];
#pragma unroll
      for (int mr = 0; mr < MR; mr++) {
        int row = waveM + mr * 16 + l16;
        af[mr] = *(const short8*)(As + row * 64 + (((kk * 4 + quad) ^ (row & 7)) * 8));
      }
#pragma unroll
      for (int nc = 0; nc < NC; nc++) {
        int row = waveN + nc * 16 + l16;
        bf8[nc] = *(const short8*)(Bs + row * 64 + (((kk * 4 + quad) ^ (row & 7)) * 8));
      }
#pragma unroll
      for (int mr = 0; mr < MR; mr++)
#pragma unroll
        for (int nc = 0; nc < NC; nc++)
          acc[mr][nc] = __builtin_amdgcn_mfma_f32_16x16x32_bf16(af[mr], bf8[nc], acc[mr][nc], 0, 0, 0);
    }
  }

  float bv[NC];
#pragma unroll
  for (int nc = 0; nc < NC; nc++) bv[nc] = bias[n0 + waveN + nc * 16 + l16];

  if (EPI == 0) {
    unsigned short* Cs = Sm;
    const int CST = 208;
    int startV = 2048 - n0;
    if (startV < 0) startV = 0;
    if (startV > TN) startV = TN;
    int chunksQK = startV >> 3;
    for (int p = 0; p < 2; p++) {
      __syncthreads();
      if ((w >> 1) == p) {
#pragma unroll
        for (int mr = 0; mr < MR; mr++)
#pragma unroll
          for (int nc = 0; nc < NC; nc++)
#pragma unroll
            for (int r = 0; r < 4; r++) {
              int lrow = mr * 16 + quad * 4 + r;
              int lcol = waveN + nc * 16 + l16;
              Cs[lrow * CST + (((lcol >> 3) ^ (quad << 1)) * 8) + (lcol & 7)] =
                  f2bf(acc[mr][nc][r] + bv[nc]);
            }
      }
      __syncthreads();
      {
        int lr = t & 63, gm = m0 + p * 64 + lr;
        int rot = ((lr >> 2) & 3) << 1;
        bool okm = (gm < MTOK);
        int bb = (unsigned)gm / 1023u;
        int s = gm - bb * 1023;
        for (int c8 = (t >> 6); c8 < chunksQK; c8 += 4) {
          short8 v = *(const short8*)(Cs + lr * CST + ((c8 ^ rot) * 8));
          int gn = n0 + c8 * 8;
          unsigned short* dst = (gn >> 10) ? Kb : Qb;
          int e = gn & 1023;
          int h = e >> 6, d0 = e & 63;
          if (okm) *(short8*)(dst + ((bb * HEADS + h) * SK + s) * HDIM + d0) = v;
        }
      }
      {
        int tok = t & 63, gm = m0 + p * 64 + tok;
        int rot = ((tok >> 2) & 3) << 1;
        bool okm = (gm < MTOK);
        int bb = (unsigned)gm / 1023u;
        int s = gm - bb * 1023;
        for (int c = startV + (t >> 6); c < TN; c += 4) {
          unsigned short val = Cs[tok * CST + (((c >> 3) ^ rot) * 8) + (c & 7)];
          int e = (n0 + c) & 1023;
          int h = e >> 6, d0 = e & 63;
          if (okm) VtOut[((bb * HEADS + h) * HDIM + d0) * SK + s] = val;
        }
      }
    }
  } else {
#pragma unroll
    for (int nc = 0; nc < NC; nc++) {
      int gn = n0 + waveN + nc * 16 + l16;
#pragma unroll
      for (int mr = 0; mr < MR; mr++) {
#pragma unroll
        for (int r = 0; r < 4; r++) {
          int gm = m0 + waveM + mr * 16 + quad * 4 + r;
          if (gm < MTOK) out[gm * EMBED + gn] = acc[mr][nc][r] + bv[nc];
        }
      }
    }
  }
}

// ---------------- flash attention ----------------
// Fixed-shift softmax (m = image score; alpha == 1; masked entries underflow to 0;
// row-sum reduced once at the end). 40KB LDS. launch_bounds(256,3): R9's (256,4)
// capped registers -> scratch spills (WRITE_SIZE 8->31MB); 3 leaves compiler at
// ~80 VGPR (no spill) while LDS still permits 4 blocks/CU.
__global__ __launch_bounds__(256, 3) void k_flash(
    const unsigned short* __restrict__ Qb, const unsigned short* __restrict__ Kb,
    const unsigned short* __restrict__ Vtg, const float* __restrict__ am,
    unsigned short* __restrict__ Ao) {
  __shared__ __attribute__((aligned(16))) unsigned short Ks[8192];   // [128][64] xor-swz
  __shared__ __attribute__((aligned(16))) unsigned short Vs[8192];   // [64 d][128 key] xor-swz
  __shared__ __attribute__((aligned(16))) unsigned short Ps[4096];   // 4 waves x [16][64] xor-swz

  int t = threadIdx.x, lane = t & 63, w = t >> 6;
  int quad = lane >> 4, l16 = lane & 15;
  int B = blockIdx.x;
  int bh = (B & 7) | (((B >> 3) & 7) << 3);
  int tq = 15 - (B >> 6);             // heavy blocks dispatch first
  int bb = bh >> 4, h = bh & 15;

  const float SCL = 0.18033688011f;     // 0.125 * log2(e)
  const float MASKV = -14426.950408f;   // -10000 * log2(e)
  const float L2E = 1.44269504089f;

  // Q fragments in registers (row 1023 is the zeroed pad)
  short8 qf[2];
  {
    int qrow = tq * 64 + w * 16 + l16;
#pragma unroll
    for (int kk = 0; kk < 2; kk++)
      qf[kk] = *(const short8*)(Qb + (bh * SK + qrow) * HDIM + (kk * 4 + quad) * 8);
  }

  // image init: m = (q . k_img)*SCL (fixed shift), implicit p_img = 1, O = v_img
  float m_i[4];
  floatx4 acc_o[4];
  {
    float s0 = 0.f;
#pragma unroll
    for (int kk = 0; kk < 2; kk++) {
      short8 ki = *(const short8*)(Kb + (bh * SK + (SK - 1)) * HDIM + (kk * 4 + quad) * 8);
#pragma unroll
      for (int j = 0; j < 8; j++)
        s0 += bf2f((unsigned short)qf[kk][j]) * bf2f((unsigned short)ki[j]);
    }
    s0 += __shfl_xor(s0, 16);
    s0 += __shfl_xor(s0, 32);
    s0 *= SCL;
#pragma unroll
    for (int r = 0; r < 4; r++) m_i[r] = __shfl(s0, quad * 4 + r);
#pragma unroll
    for (int n = 0; n < 4; n++) {
      float vf = bf2f(Vtg[(bh * HDIM + n * 16 + l16) * SK + (SK - 1)]);
#pragma unroll
      for (int e = 0; e < 4; e++) acc_o[n][e] = vf;
    }
  }

  float rsum_t[4] = {0.f, 0.f, 0.f, 0.f};   // per-lane partial, reduced once at end
  unsigned short* Pw = Ps + w * 1024;       // [16][64] per wave
  const float* amb = am + bb * SQ;
  int jmax = tq >> 1;

  for (int j = 0; j <= jmax; j++) {
    __syncthreads();   // prior readers done (drains pending GLDs too)
#pragma unroll
    for (int i = 0; i < 4; i++) {
      int r = i * 32 + (t >> 3), gc = (t & 7) ^ (r & 7);
      gld16(Kb + (bh * SK + j * 128 + r) * HDIM + gc * 8, Ks + i * 2048 + t * 8);
    }
#pragma unroll
    for (int i = 0; i < 4; i++) {
      int d = i * 16 + (t >> 4), gc = (t & 15) ^ (d & 7);
      gld16(Vtg + (bh * HDIM + d) * SK + j * 128 + gc * 8, Vs + i * 2048 + t * 8);
    }
    __syncthreads();

    bool diag = (j == jmax);
    int qmaxw = tq * 64 + w * 16 + 15;   // max q row this wave owns

    floatx4 sacc[8];
#pragma unroll
    for (int n = 0; n < 8; n++)
#pragma unroll
      for (int e = 0; e < 4; e++) sacc[n][e] = 0.f;
#pragma unroll
    for (int nc = 0; nc < 8; nc++) {
      if (j * 128 + nc * 16 <= qmaxw) {
        int krow = nc * 16 + l16;
#pragma unroll
        for (int kk = 0; kk < 2; kk++) {
          short8 b = *(const short8*)(Ks + krow * 64 + (((kk * 4 + quad) ^ (krow & 7)) * 8));
          sacc[nc] = __builtin_amdgcn_mfma_f32_16x16x32_bf16(qf[kk], b, sacc[nc], 0, 0, 0);
        }
      }
    }

    // p = exp2(sc - m_fixed); masked entries underflow to exactly 0.
    int qbase = tq * 64 + w * 16 + quad * 4;
#pragma unroll
    for (int nc = 0; nc < 8; nc++) {
      if (j * 128 + nc * 16 <= qmaxw) {     // dead nc: sacc stays 0 (never QK'd)
        int s = j * 128 + nc * 16 + l16;
        float amv = (s < SQ) ? amb[s] * L2E : 0.f;
#pragma unroll
        for (int r = 0; r < 4; r++) {
          float sc = sacc[nc][r] * SCL + amv;
          if (diag && s > qbase + r) sc = MASKV;
          float p = __builtin_amdgcn_exp2f(sc - m_i[r]);
          sacc[nc][r] = p;
          rsum_t[r] += p;
        }
      }
    }

    // P pack + PV in two 64-key halves (Pw reused; in-wave DS order = safe)
#pragma unroll
    for (int hh = 0; hh < 2; hh++) {
      if (j * 128 + hh * 64 <= qmaxw) {
#pragma unroll
        for (int nc2 = 0; nc2 < 4; nc2++) {
          int nc = hh * 4 + nc2;
#pragma unroll
          for (int r = 0; r < 4; r++) {
            int row = quad * 4 + r;
            union { float f; unsigned u; } cv; cv.f = sacc[nc][r];
            Pw[row * 64 + (((nc2 * 2 + (l16 >> 3)) ^ (row & 7)) * 8) + (l16 & 7)] =
                (unsigned short)(cv.u >> 16);
          }
        }
#pragma unroll
        for (int k2 = 0; k2 < 2; k2++) {
          int kk2 = hh * 2 + k2;
          short8 a = *(const short8*)(Pw + l16 * 64 + (((k2 * 4 + quad) ^ (l16 & 7)) * 8));
#pragma unroll
          for (int n = 0; n < 4; n++) {
            int vrow = n * 16 + l16;
            short8 b = *(const short8*)(Vs + vrow * 128 + (((kk2 * 4 + quad) ^ (vrow & 7)) * 8));
            acc_o[n] = __builtin_amdgcn_mfma_f32_16x16x32_bf16(a, b, acc_o[n], 0, 0, 0);
          }
        }
      }
    }
  }

  // single final row-reduce of the sum; l = 1 (image) + rsum
  float inv[4];
#pragma unroll
  for (int r = 0; r < 4; r++) {
    float o = rsum_t[r];
    o += rorf<0x121>(o);
    o += rorf<0x122>(o);
    o += rorf<0x124>(o);
    o += rorf<0x128>(o);
    inv[r] = 1.f / (1.f + o);
  }

  // normalize, repack via LDS (Os overlays Ps), vectorized store
  unsigned short* Os = Ps;   // [64][64], "+row" chunk rotation
  __syncthreads();
#pragma unroll
  for (int n = 0; n < 4; n++)
#pragma unroll
    for (int r = 0; r < 4; r++) {
      int row = w * 16 + quad * 4 + r, col = n * 16 + l16;
      Os[row * 64 + ((((col >> 3) + row) & 7) * 8) + (col & 7)] = f2bf(acc_o[n][r] * inv[r]);
    }
  __syncthreads();
#pragma unroll
  for (int i = 0; i < 2; i++) {
    int cid = i * 256 + t, r = cid >> 3, c8 = cid & 7;
    int q = tq * 64 + r;
    if (q < SQ) {
      short8 v = *(const short8*)(Os + r * 64 + (((c8 + r) & 7) * 8));
      *(short8*)(Ao + (bb * SQ + q) * EMBED + h * HDIM + c8 * 8) = v;
    }
  }
}

// ---------------- launch ----------------
extern "C" void kernel_launch(void* const* d_in, const int* in_sizes, int n_in,
                              void* d_out, int out_size, void* d_ws, size_t ws_size,
                              hipStream_t stream) {
  const float* word   = (const float*)d_in[0];
  const float* img    = (const float*)d_in[1];
  const float* amask  = (const float*)d_in[2];
  const float* attn_w = (const float*)d_in[3];
  const float* attn_b = (const float*)d_in[4];
  const float* proj_w = (const float*)d_in[5];
  const float* proj_b = (const float*)d_in[6];
  const float* ukw    = (const float*)d_in[7];
  const float* ukb    = (const float*)d_in[8];
  const float* uvw    = (const float*)d_in[9];
  const float* uvb    = (const float*)d_in[10];
  float* out = (float*)d_out;

  char* ws = (char*)d_ws;
  unsigned short* Aw     = (unsigned short*)(ws);                 // [0,8MB) A / later Ao
  unsigned short* WtAttn = (unsigned short*)(ws + 8388608);       // [8,14MB)
  unsigned short* WtProj = (unsigned short*)(ws + 14680064);      // [14,16MB)
  unsigned short* Qb     = (unsigned short*)(ws + 16777216);      // [16,24MB)
  unsigned short* Kb     = (unsigned short*)(ws + 25165824);      // [24,32MB) row 1023 = k_img
  unsigned short* Vtg    = (unsigned short*)(ws + 33554432);      // [32,40MB) V^T, col 1023 = v_img
  unsigned short* Ao     = Aw;  // reuse: A dead after QKV GEMM

  k_prep<<<8208, 256, 0, stream>>>(word, attn_w, proj_w, img, ukw, ukb, uvw, uvb,
                                   Aw, WtAttn, WtProj, Qb, Kb, Vtg);
  k_gemm<0, 128, 192><<<dim3(16, 32), 256, 0, stream>>>(Aw, WtAttn, 1024, attn_b, Qb, Kb, Vtg, nullptr);
  k_flash<<<1024, 256, 0, stream>>>(Qb, Kb, Vtg, amask, Ao);
  k_gemm<1, 64, 128><<<dim3(8, 64), 256, 0, stream>>>(Ao, WtProj, 1024, proj_b, nullptr, nullptr, nullptr, out);
}